// Round 3
// baseline (455.997 us; speedup 1.0000x reference)
//
#include <hip/hip_runtime.h>
#include <hip/hip_bf16.h>
#include <hip/hip_fp16.h>
#include <math.h>

// Problem constants
#define DD   1024
#define EE   8
#define HH   512
#define NTOK 16384        // B*T
#define NG   16           // (expert, slot) groups
#define MAXMT 24          // max 128-row tiles per group (n_g ~ 2048 +- ~200)
#define NT   (NG * MAXMT) // 384 tiles; 384 % 8 == 0 -> slice-major keeps same-tile slices on one XCD

typedef __attribute__((ext_vector_type(8))) short short8;   // 8 bf16
typedef __attribute__((ext_vector_type(4))) float floatx4;  // MFMA C/D frag

__device__ __forceinline__ ushort f2bfu(float f) {
    __hip_bfloat16 h = __float2bfloat16(f);   // RNE
    return *reinterpret_cast<ushort*>(&h);
}
__device__ __forceinline__ float bfu2f(ushort u) {
    union { unsigned u; float f; } cv; cv.u = ((unsigned)u) << 16; return cv.f;
}

// async global->LDS, 16B per lane. LDS dest = wave-uniform base + lane*16.
__device__ __forceinline__ void glds16(const void* g, void* l) {
    __builtin_amdgcn_global_load_lds(
        (const __attribute__((address_space(1))) unsigned int*)g,
        (__attribute__((address_space(3))) unsigned int*)l, 16, 0, 0);
}

// ---------------------------------------------------------------------------
// Kernel 1: per-expert transpose + cvt: src [E][R][C] fp32 -> dst [E][C][R] bf16
// First launch also zeroes the 256-int counter region.
// ---------------------------------------------------------------------------
__global__ __launch_bounds__(256) void trans_k(const float* __restrict__ src, ushort* __restrict__ dst,
                                               const int R, const int C, int* __restrict__ cnt) {
    if (cnt && blockIdx.x == 0 && blockIdx.y == 0 && blockIdx.z == 0 && threadIdx.x < 256)
        cnt[threadIdx.x] = 0;
    const int e = blockIdx.z, r0 = blockIdx.y * 64, c0 = blockIdx.x * 64;
    __shared__ float t[64][65];
    const int tid = threadIdx.x;
    const int cseg = (tid & 15) * 4, rr = tid >> 4;
#pragma unroll
    for (int j = 0; j < 4; ++j) {
        const int r = rr + j * 16;
        const float4 v = *(const float4*)(src + ((size_t)e * R + r0 + r) * C + c0 + cseg);
        t[r][cseg] = v.x; t[r][cseg+1] = v.y; t[r][cseg+2] = v.z; t[r][cseg+3] = v.w;
    }
    __syncthreads();
    const int rseg = (tid & 15) * 4;
#pragma unroll
    for (int j = 0; j < 4; ++j) {
        const int crow = (tid >> 4) + j * 16;
        ushort o[4];
#pragma unroll
        for (int q = 0; q < 4; ++q) o[q] = f2bfu(t[rseg + q][crow]);
        *(uint2*)(dst + ((size_t)e * C + c0 + crow) * R + r0 + rseg) = *(uint2*)o;
    }
}

// ---------------------------------------------------------------------------
// Kernel 2: router (fp32 math) + x -> bf16 conversion fused. Weights staged
// in LDS (WT[d][20] fp32, 80 KB, bank-minimal b128 reads); 512 thr = 8 waves
// x 2 tokens. entry = tok | gate_f16 << 16, group g = expert*2 + slot.
// ---------------------------------------------------------------------------
#define ROUTER_TAIL(AR, AN, T) do {                                           \
    const int t_ = (T);                                                       \
    float noisy[EE];                                                          \
    _Pragma("unroll")                                                         \
    for (int e = 0; e < EE; ++e) {                                            \
        const float lg = AR[e] + br[e];                                       \
        const float nl = AN[e] + bn[e];                                       \
        const float sp = fmaxf(nl, 0.f) + log1pf(expf(-fabsf(nl)));           \
        noisy[e] = lg + noise[(size_t)t_ * EE + e] * sp;                      \
    }                                                                         \
    int i0 = 0;                                                               \
    _Pragma("unroll")                                                         \
    for (int e = 1; e < EE; ++e) if (noisy[e] > noisy[i0]) i0 = e;            \
    int i1 = (i0 == 0) ? 1 : 0;                                               \
    _Pragma("unroll")                                                         \
    for (int e = 0; e < EE; ++e) if (e != i0 && noisy[e] > noisy[i1]) i1 = e; \
    const float ex = expf(noisy[i1] - noisy[i0]);                             \
    const float g0 = 1.f / (1.f + ex);                                        \
    const float g1 = ex / (1.f + ex);                                         \
    __half h0 = __float2half_rn(g0), h1 = __float2half_rn(g1);                \
    const unsigned u0 = (unsigned)t_ | ((unsigned)*reinterpret_cast<ushort*>(&h0) << 16); \
    const unsigned u1 = (unsigned)t_ | ((unsigned)*reinterpret_cast<ushort*>(&h1) << 16); \
    const int ga = i0 * 2 + 0, gb = i1 * 2 + 1;                               \
    int p0 = atomicAdd(&cnt[ga * 16], 1);                                     \
    entries[ga * NTOK + p0] = u0;                                             \
    int p1 = atomicAdd(&cnt[gb * 16], 1);                                     \
    entries[gb * NTOK + p1] = u1;                                             \
} while (0)

__global__ __launch_bounds__(512) void router_k(
    const float* __restrict__ x, const float* __restrict__ Wr, const float* __restrict__ br,
    const float* __restrict__ Wn, const float* __restrict__ bn, const float* __restrict__ noise,
    int* __restrict__ cnt, unsigned* __restrict__ entries, ushort* __restrict__ xb)
{
    __shared__ __align__(16) float WT[DD * 20];   // 80 KB

    const int tid = threadIdx.x;
    // ---- stage Wr/Wn -> WT[d][20] (coalesced global float4 reads) ----
    {
        const int d0 = tid * 2;
#pragma unroll
        for (int r = 0; r < 2; ++r) {
            const int d = d0 + r;
            float4 a = *(const float4*)(Wr + (size_t)d * EE);
            float4 b = *(const float4*)(Wr + (size_t)d * EE + 4);
            float4 c = *(const float4*)(Wn + (size_t)d * EE);
            float4 e4 = *(const float4*)(Wn + (size_t)d * EE + 4);
            float* row = &WT[d * 20];
            *(float4*)(row + 0)  = a;
            *(float4*)(row + 4)  = b;
            *(float4*)(row + 8)  = c;
            *(float4*)(row + 12) = e4;
        }
    }
    __syncthreads();

    const int wave = tid >> 6;
    const int lane = tid & 63;
    const int t0 = blockIdx.x * 16 + wave * 2;

    float a0r[EE], a0n[EE], a1r[EE], a1n[EE];
#pragma unroll
    for (int e = 0; e < EE; ++e) { a0r[e] = 0.f; a0n[e] = 0.f; a1r[e] = 0.f; a1n[e] = 0.f; }

    const float* xr0 = x + (size_t)t0 * DD;
    const float* xr1 = xr0 + DD;
    ushort* xb0 = xb + (size_t)t0 * DD;
    ushort* xb1 = xb0 + DD;

#pragma unroll 4
    for (int s = 0; s < DD / 64; ++s) {
        const int d = s * 64 + lane;
        const float x0 = xr0[d];
        const float x1 = xr1[d];
        xb0[d] = f2bfu(x0);
        xb1[d] = f2bfu(x1);
        const float* row = &WT[d * 20];
        const float4 w0 = *(const float4*)(row + 0);    // Wr e0-3
        const float4 w1 = *(const float4*)(row + 4);    // Wr e4-7
        const float4 w2 = *(const float4*)(row + 8);    // Wn e0-3
        const float4 w3 = *(const float4*)(row + 12);   // Wn e4-7
        const float wr[8] = { w0.x, w0.y, w0.z, w0.w, w1.x, w1.y, w1.z, w1.w };
        const float wn[8] = { w2.x, w2.y, w2.z, w2.w, w3.x, w3.y, w3.z, w3.w };
#pragma unroll
        for (int e = 0; e < EE; ++e) {
            a0r[e] = fmaf(x0, wr[e], a0r[e]);
            a0n[e] = fmaf(x0, wn[e], a0n[e]);
            a1r[e] = fmaf(x1, wr[e], a1r[e]);
            a1n[e] = fmaf(x1, wn[e], a1n[e]);
        }
    }
#pragma unroll
    for (int off = 32; off > 0; off >>= 1) {
#pragma unroll
        for (int e = 0; e < EE; ++e) {
            a0r[e] += __shfl_xor(a0r[e], off);
            a0n[e] += __shfl_xor(a0n[e], off);
            a1r[e] += __shfl_xor(a1r[e], off);
            a1n[e] += __shfl_xor(a1n[e], off);
        }
    }
    if (lane == 0) {
        ROUTER_TAIL(a0r, a0n, t0);
        ROUTER_TAIL(a1r, a1n, t0 + 1);
    }
}

// ---------------------------------------------------------------------------
// Grouped GEMM: 128x128x64 tile, 4 waves (2x2), XOR-swizzled LDS.
// v4: (a) 2-phase double-buffered prefetch: STAGE(next K-tile) issued BEFORE
//     the ds_read+MFMA of the current tile, ONE __syncthreads per K-step
//     (its vmcnt(0) drain waits on the prefetch whose latency was hidden
//     under compute). Old structure exposed full stage latency each step
//     -> MfmaUtil 13%, 321 TF (= m102 shape-curve point).
//     (b) slice-major grid decode: slice = bx / NT, tile = bx % NT.
//     NT = 384 == 0 (mod 8) -> all n-slices of one (g,tm) tile share bx%8
//     -> same XCD -> shared A-tile fetched into ONE L2 (was 4/8 XCDs ->
//     FETCH_SIZE 124 MB, ~3-4x A amplification).
// offsets folded: each block prefix-sums the 16 L2-hot counters.
// ---------------------------------------------------------------------------

// Kernel 4: down: hid[off+row][n] = gelu(x_gathered @ WdT^T + bd)
// grid: bx = n0q*NT + (g*MAXMT + tm), n0 = n0q*128
__global__ __launch_bounds__(256) void down_k(
    const ushort* __restrict__ xb, const ushort* __restrict__ WdT, const float* __restrict__ bd,
    const int* __restrict__ cnt, const unsigned* __restrict__ entries, ushort* __restrict__ hid)
{
    const int bx = blockIdx.x;
    const int n0 = (bx / NT) * 128;
    const int tmg = bx % NT;
    const int tm = tmg % MAXMT;
    const int g = tmg / MAXMT, e = g >> 1;
    const int n_g = cnt[g * 16];
    if (tm * 128 >= n_g) return;

    int og = 0;
    for (int gg = 0; gg < g; ++gg) og += cnt[gg * 16];   // exclusive prefix

    __shared__ __align__(16) ushort As[2 * 128 * 64];
    __shared__ __align__(16) ushort Bs[2 * 128 * 64];
    __shared__ unsigned ecache[128];

    const int tid = threadIdx.x, lane = tid & 63, w = tid >> 6;
    const int wm = w >> 1, wn = w & 1;
    const int fr = lane & 15, fq = lane >> 4;

    if (tid < 128) {
        const int ridx = min(tm * 128 + tid, n_g - 1);
        ecache[tid] = entries[g * NTOK + ridx];
    }
    __syncthreads();

    const int lr = lane >> 3, seg = lane & 7;
    const int slog = seg ^ lr;                 // row&7 == lr for all j
    const ushort* gA[4]; const ushort* gB[4];
    int loff[4];
    const ushort* WTe = WdT + (size_t)e * HH * DD;
#pragma unroll
    for (int j = 0; j < 4; ++j) {
        const int row = w * 32 + j * 8 + lr;
        const int tok = (int)(ecache[row] & 0xFFFFu);
        gA[j] = xb + (size_t)tok * DD + slog * 8;
        gB[j] = WTe + (size_t)(n0 + row) * DD + slog * 8;
        loff[j] = (w * 256 + j * 64) * 16;     // byte offset within one buffer
    }

    floatx4 acc[4][4];
#pragma unroll
    for (int i = 0; i < 4; ++i)
#pragma unroll
        for (int j = 0; j < 4; ++j) acc[i][j] = (floatx4){0.f, 0.f, 0.f, 0.f};

    const int axr = wm * 64 + fr;
    const int bxr = wn * 64 + fr;

    // prologue: stage K-tile 0 into buffer 0
#pragma unroll
    for (int j = 0; j < 4; ++j) {
        glds16(gA[j], (char*)As + loff[j]);
        glds16(gB[j], (char*)Bs + loff[j]);
    }
    __syncthreads();

    int cur = 0;
    for (int k0 = 0; k0 < DD; k0 += 64) {
        // prefetch next K-tile into the other buffer (overlaps compute below)
        if (k0 + 64 < DD) {
            const int nb = (cur ^ 1) * 16384;  // byte offset of other buffer
#pragma unroll
            for (int j = 0; j < 4; ++j) {
                glds16(gA[j] + k0 + 64, (char*)As + nb + loff[j]);
                glds16(gB[j] + k0 + 64, (char*)Bs + nb + loff[j]);
            }
        }
        const int cb = cur * 8192;             // ushort offset of current buffer
#pragma unroll
        for (int kh = 0; kh < 2; ++kh) {
            short8 a[4], b[4];
#pragma unroll
            for (int mt = 0; mt < 4; ++mt) {
                const int r = axr + mt * 16;
                a[mt] = *(const short8*)&As[cb + r * 64 + ((kh * 4 + fq) ^ (r & 7)) * 8];
            }
#pragma unroll
            for (int nt = 0; nt < 4; ++nt) {
                const int r = bxr + nt * 16;
                b[nt] = *(const short8*)&Bs[cb + r * 64 + ((kh * 4 + fq) ^ (r & 7)) * 8];
            }
#pragma unroll
            for (int mt = 0; mt < 4; ++mt)
#pragma unroll
                for (int nt = 0; nt < 4; ++nt)
                    acc[mt][nt] = __builtin_amdgcn_mfma_f32_16x16x32_bf16(a[mt], b[nt], acc[mt][nt], 0, 0, 0);
        }
        __syncthreads();   // prefetch landed + everyone done reading cur
        cur ^= 1;
    }

    const int hbase = og + tm * 128;
#pragma unroll
    for (int nt = 0; nt < 4; ++nt) {
        const int n = n0 + wn * 64 + nt * 16 + fr;
        const float bias = bd[e * HH + n];
#pragma unroll
        for (int mt = 0; mt < 4; ++mt)
#pragma unroll
            for (int i = 0; i < 4; ++i) {
                const int rl = wm * 64 + mt * 16 + fq * 4 + i;
                if (tm * 128 + rl < n_g) {
                    const float v = acc[mt][nt][i] + bias;
                    const float ge = 0.5f * v * (1.f + erff(v * 0.7071067811865475f));
                    hid[(size_t)(hbase + rl) * HH + n] = f2bfu(ge);
                }
            }
    }
}

// Kernel 5: up, SINGLE pass over all 16 groups:
//   slots[tok*2+slot][n] = (hid @ WuT^T + bu) * gate   (bf16, write-only)
// grid: bx = n0q*NT + (g*MAXMT + tm), n0 = n0q*128
__global__ __launch_bounds__(256) void up_k(
    const ushort* __restrict__ hid, const ushort* __restrict__ WuT, const float* __restrict__ bu,
    const int* __restrict__ cnt, const unsigned* __restrict__ entries, ushort* __restrict__ slots)
{
    const int bx = blockIdx.x;
    const int n0 = (bx / NT) * 128;
    const int tmg = bx % NT;
    const int tm = tmg % MAXMT;
    const int g = tmg / MAXMT, e = g >> 1, slot = g & 1;
    const int n_g = cnt[g * 16];
    if (tm * 128 >= n_g) return;

    int hbase = 0;
    for (int gg = 0; gg < g; ++gg) hbase += cnt[gg * 16];  // exclusive prefix

    __shared__ __align__(16) ushort As[2 * 128 * 64];
    __shared__ __align__(16) ushort Bs[2 * 128 * 64];
    __shared__ unsigned ecache[128];

    const int tid = threadIdx.x, lane = tid & 63, w = tid >> 6;
    const int wm = w >> 1, wn = w & 1;
    const int fr = lane & 15, fq = lane >> 4;

    if (tid < 128) {
        const int ridx = min(tm * 128 + tid, n_g - 1);
        ecache[tid] = entries[g * NTOK + ridx];
    }
    __syncthreads();

    const int lr = lane >> 3, seg = lane & 7;
    const int slog = seg ^ lr;
    const ushort* gA[4]; const ushort* gB[4];
    int loff[4];
    const ushort* WTe = WuT + (size_t)e * DD * HH;
#pragma unroll
    for (int j = 0; j < 4; ++j) {
        const int row = w * 32 + j * 8 + lr;
        const int ar = min(tm * 128 + row, n_g - 1);
        gA[j] = hid + (size_t)(hbase + ar) * HH + slog * 8;
        gB[j] = WTe + (size_t)(n0 + row) * HH + slog * 8;
        loff[j] = (w * 256 + j * 64) * 16;
    }

    floatx4 acc[4][4];
#pragma unroll
    for (int i = 0; i < 4; ++i)
#pragma unroll
        for (int j = 0; j < 4; ++j) acc[i][j] = (floatx4){0.f, 0.f, 0.f, 0.f};

    const int axr = wm * 64 + fr;
    const int bxr = wn * 64 + fr;

    // prologue: stage K-tile 0 into buffer 0
#pragma unroll
    for (int j = 0; j < 4; ++j) {
        glds16(gA[j], (char*)As + loff[j]);
        glds16(gB[j], (char*)Bs + loff[j]);
    }
    __syncthreads();

    int cur = 0;
    for (int k0 = 0; k0 < HH; k0 += 64) {
        if (k0 + 64 < HH) {
            const int nb = (cur ^ 1) * 16384;
#pragma unroll
            for (int j = 0; j < 4; ++j) {
                glds16(gA[j] + k0 + 64, (char*)As + nb + loff[j]);
                glds16(gB[j] + k0 + 64, (char*)Bs + nb + loff[j]);
            }
        }
        const int cb = cur * 8192;
#pragma unroll
        for (int kh = 0; kh < 2; ++kh) {
            short8 a[4], b[4];
#pragma unroll
            for (int mt = 0; mt < 4; ++mt) {
                const int r = axr + mt * 16;
                a[mt] = *(const short8*)&As[cb + r * 64 + ((kh * 4 + fq) ^ (r & 7)) * 8];
            }
#pragma unroll
            for (int nt = 0; nt < 4; ++nt) {
                const int r = bxr + nt * 16;
                b[nt] = *(const short8*)&Bs[cb + r * 64 + ((kh * 4 + fq) ^ (r & 7)) * 8];
            }
#pragma unroll
            for (int mt = 0; mt < 4; ++mt)
#pragma unroll
                for (int nt = 0; nt < 4; ++nt)
                    acc[mt][nt] = __builtin_amdgcn_mfma_f32_16x16x32_bf16(a[mt], b[nt], acc[mt][nt], 0, 0, 0);
        }
        __syncthreads();
        cur ^= 1;
    }

#pragma unroll
    for (int nt = 0; nt < 4; ++nt) {
        const int n = n0 + wn * 64 + nt * 16 + fr;
        const float bias = bu[e * DD + n];
#pragma unroll
        for (int mt = 0; mt < 4; ++mt)
#pragma unroll
            for (int i = 0; i < 4; ++i) {
                const int rl = wm * 64 + mt * 16 + fq * 4 + i;
                if (tm * 128 + rl < n_g) {
                    const unsigned en = ecache[rl];
                    const int tok = (int)(en & 0xFFFFu);
                    ushort hb = (ushort)(en >> 16);
                    const float gate = __half2float(*reinterpret_cast<__half*>(&hb));
                    const float v = (acc[mt][nt][i] + bias) * gate;
                    slots[((size_t)tok * 2 + slot) * DD + n] = f2bfu(v);
                }
            }
    }
}

// Kernel 6: out[t][d] = slots[2t][d] + slots[2t+1][d]  (fp32 out, 8 elems/thread)
__global__ __launch_bounds__(256) void combine_k(
    const ushort* __restrict__ slots, float* __restrict__ out)
{
    const size_t flat = ((size_t)blockIdx.x * 256 + threadIdx.x) * 8;
    const size_t t = flat >> 10;         // / DD
    const size_t d = flat & (DD - 1);
    union { uint4 v; ushort h[8]; } a, b;
    a.v = *(const uint4*)(slots + ((t * 2 + 0) << 10) + d);
    b.v = *(const uint4*)(slots + ((t * 2 + 1) << 10) + d);
    float o[8];
#pragma unroll
    for (int j = 0; j < 8; ++j) o[j] = bfu2f(a.h[j]) + bfu2f(b.h[j]);
    *(float4*)(out + flat) = *(const float4*)&o[0];
    *(float4*)(out + flat + 4) = *(const float4*)&o[4];
}

// ---------------------------------------------------------------------------
// Workspace layout (bytes), total ~145 MB:
//   0         cnt    : int[16] @ 64B stride (256-int region zeroed by trans_k)
//   2048      entries: u32[16][16384]            (1 MB)
//   1050624   xb     : bf16 [16384][1024]        (32 MB)
//   34605056  WdT    : bf16 [8][512 h][1024 d]   (8 MB)
//   42993664  WuT    : bf16 [8][1024 d][512 h]   (8 MB)
//   51382272  hid    : bf16 [32768][512]         (32 MB)
//   84936704  slots  : bf16 [32768][1024]        (64 MB)
// ---------------------------------------------------------------------------
extern "C" void kernel_launch(void* const* d_in, const int* in_sizes, int n_in,
                              void* d_out, int out_size, void* d_ws, size_t ws_size,
                              hipStream_t stream)
{
    const float* x     = (const float*)d_in[0];
    const float* Wr    = (const float*)d_in[1];
    const float* br    = (const float*)d_in[2];
    const float* Wn    = (const float*)d_in[3];
    const float* bn    = (const float*)d_in[4];
    const float* Wd    = (const float*)d_in[5];
    const float* bd    = (const float*)d_in[6];
    const float* Wu    = (const float*)d_in[7];
    const float* bu    = (const float*)d_in[8];
    const float* noise = (const float*)d_in[9];

    char* ws = (char*)d_ws;
    int*      cnt     = (int*)(ws + 0);
    unsigned* entries = (unsigned*)(ws + 2048);
    ushort*   xb      = (ushort*)(ws + 1050624);
    ushort*   WdT     = (ushort*)(ws + 34605056);
    ushort*   WuT     = (ushort*)(ws + 42993664);
    ushort*   hid     = (ushort*)(ws + 51382272);
    ushort*   slots   = (ushort*)(ws + 84936704);

    trans_k<<<dim3(HH / 64, DD / 64, EE), 256, 0, stream>>>(Wd, WdT, DD, HH, cnt);      // [d][h]->[h][d] + zero cnt
    trans_k<<<dim3(DD / 64, HH / 64, EE), 256, 0, stream>>>(Wu, WuT, HH, DD, nullptr);  // [h][d]->[d][h]
    router_k<<<NTOK / 16, 512, 0, stream>>>(x, Wr, br, Wn, bn, noise, cnt, entries, xb);
    down_k<<<NT * 4, 256, 0, stream>>>(xb, WdT, bd, cnt, entries, hid);
    up_k<<<NT * 8, 256, 0, stream>>>(hid, WuT, bu, cnt, entries, slots);
    combine_k<<<(NTOK * DD) / (256 * 8), 256, 0, stream>>>(slots, (float*)d_out);
}

// Round 6
// 447.385 us; speedup vs baseline: 1.0192x; 1.0192x over previous
//
#include <hip/hip_runtime.h>
#include <hip/hip_bf16.h>
#include <hip/hip_fp16.h>
#include <math.h>

// Problem constants
#define DD   1024
#define EE   8
#define HH   512
#define NTOK 16384        // B*T
#define MAXMT 40          // max 128-row tiles per expert (n_e ~ 4096, sigma ~60 -> 5120 is >>safe)
#define NSL_D 4           // down: N=512  -> 4 slices of 128
#define NSL_U 8           // up:   N=1024 -> 8 slices of 128
#define NWD  (EE * MAXMT * NSL_D)   // 1280 blocks, %8==0
#define NWU  (EE * MAXMT * NSL_U)   // 2560 blocks, %8==0

typedef __attribute__((ext_vector_type(8))) short short8;   // 8 bf16
typedef __attribute__((ext_vector_type(4))) float floatx4;  // MFMA C/D frag

__device__ __forceinline__ ushort f2bfu(float f) {
    __hip_bfloat16 h = __float2bfloat16(f);   // RNE
    return *reinterpret_cast<ushort*>(&h);
}
__device__ __forceinline__ float bfu2f(ushort u) {
    union { unsigned u; float f; } cv; cv.u = ((unsigned)u) << 16; return cv.f;
}

// async global->LDS, 16B per lane. LDS dest = wave-uniform base + lane*16.
__device__ __forceinline__ void glds16(const void* g, void* l) {
    __builtin_amdgcn_global_load_lds(
        (const __attribute__((address_space(1))) unsigned int*)g,
        (__attribute__((address_space(3))) unsigned int*)l, 16, 0, 0);
}

// ---------------------------------------------------------------------------
// Kernel 1: per-expert transpose + cvt: src [E][R][C] fp32 -> dst [E][C][R] bf16
// First launch also zeroes the 256-int counter region.
// ---------------------------------------------------------------------------
__global__ __launch_bounds__(256) void trans_k(const float* __restrict__ src, ushort* __restrict__ dst,
                                               const int R, const int C, int* __restrict__ cnt) {
    if (cnt && blockIdx.x == 0 && blockIdx.y == 0 && blockIdx.z == 0 && threadIdx.x < 256)
        cnt[threadIdx.x] = 0;
    const int e = blockIdx.z, r0 = blockIdx.y * 64, c0 = blockIdx.x * 64;
    __shared__ float t[64][65];
    const int tid = threadIdx.x;
    const int cseg = (tid & 15) * 4, rr = tid >> 4;
#pragma unroll
    for (int j = 0; j < 4; ++j) {
        const int r = rr + j * 16;
        const float4 v = *(const float4*)(src + ((size_t)e * R + r0 + r) * C + c0 + cseg);
        t[r][cseg] = v.x; t[r][cseg+1] = v.y; t[r][cseg+2] = v.z; t[r][cseg+3] = v.w;
    }
    __syncthreads();
    const int rseg = (tid & 15) * 4;
#pragma unroll
    for (int j = 0; j < 4; ++j) {
        const int crow = (tid >> 4) + j * 16;
        ushort o[4];
#pragma unroll
        for (int q = 0; q < 4; ++q) o[q] = f2bfu(t[rseg + q][crow]);
        *(uint2*)(dst + ((size_t)e * C + c0 + crow) * R + r0 + rseg) = *(uint2*)o;
    }
}

// ---------------------------------------------------------------------------
// Kernel 2: router (fp32 math) + x -> bf16 conversion fused. Weights staged
// in LDS (WT[d][20] fp32, 80 KB, bank-minimal b128 reads); 512 thr = 8 waves
// x 2 tokens.
// Groups merged per expert (8 groups). entry = tok | slot<<14 | gate<<16
// (tok fits 14 bits: NTOK=16384). slot 0 = top1, slot 1 = top2.
// ---------------------------------------------------------------------------
#define ROUTER_TAIL(AR, AN, T) do {                                           \
    const int t_ = (T);                                                       \
    float noisy[EE];                                                          \
    _Pragma("unroll")                                                         \
    for (int e = 0; e < EE; ++e) {                                            \
        const float lg = AR[e] + br[e];                                       \
        const float nl = AN[e] + bn[e];                                       \
        const float sp = fmaxf(nl, 0.f) + log1pf(expf(-fabsf(nl)));           \
        noisy[e] = lg + noise[(size_t)t_ * EE + e] * sp;                      \
    }                                                                         \
    int i0 = 0;                                                               \
    _Pragma("unroll")                                                         \
    for (int e = 1; e < EE; ++e) if (noisy[e] > noisy[i0]) i0 = e;            \
    int i1 = (i0 == 0) ? 1 : 0;                                               \
    _Pragma("unroll")                                                         \
    for (int e = 0; e < EE; ++e) if (e != i0 && noisy[e] > noisy[i1]) i1 = e; \
    const float ex = expf(noisy[i1] - noisy[i0]);                             \
    const float g0 = 1.f / (1.f + ex);                                        \
    const float g1 = ex / (1.f + ex);                                         \
    __half h0 = __float2half_rn(g0), h1 = __float2half_rn(g1);                \
    const unsigned u0 = (unsigned)t_ | ((unsigned)*reinterpret_cast<ushort*>(&h0) << 16); \
    const unsigned u1 = (unsigned)t_ | (1u << 14) | ((unsigned)*reinterpret_cast<ushort*>(&h1) << 16); \
    int p0 = atomicAdd(&cnt[i0 * 16], 1);                                     \
    entries[i0 * NTOK + p0] = u0;                                             \
    int p1 = atomicAdd(&cnt[i1 * 16], 1);                                     \
    entries[i1 * NTOK + p1] = u1;                                             \
} while (0)

__global__ __launch_bounds__(512) void router_k(
    const float* __restrict__ x, const float* __restrict__ Wr, const float* __restrict__ br,
    const float* __restrict__ Wn, const float* __restrict__ bn, const float* __restrict__ noise,
    int* __restrict__ cnt, unsigned* __restrict__ entries, ushort* __restrict__ xb)
{
    __shared__ __align__(16) float WT[DD * 20];   // 80 KB

    const int tid = threadIdx.x;
    // ---- stage Wr/Wn -> WT[d][20] (coalesced global float4 reads) ----
    {
        const int d0 = tid * 2;
#pragma unroll
        for (int r = 0; r < 2; ++r) {
            const int d = d0 + r;
            float4 a = *(const float4*)(Wr + (size_t)d * EE);
            float4 b = *(const float4*)(Wr + (size_t)d * EE + 4);
            float4 c = *(const float4*)(Wn + (size_t)d * EE);
            float4 e4 = *(const float4*)(Wn + (size_t)d * EE + 4);
            float* row = &WT[d * 20];
            *(float4*)(row + 0)  = a;
            *(float4*)(row + 4)  = b;
            *(float4*)(row + 8)  = c;
            *(float4*)(row + 12) = e4;
        }
    }
    __syncthreads();

    const int wave = tid >> 6;
    const int lane = tid & 63;
    const int t0 = blockIdx.x * 16 + wave * 2;

    float a0r[EE], a0n[EE], a1r[EE], a1n[EE];
#pragma unroll
    for (int e = 0; e < EE; ++e) { a0r[e] = 0.f; a0n[e] = 0.f; a1r[e] = 0.f; a1n[e] = 0.f; }

    const float* xr0 = x + (size_t)t0 * DD;
    const float* xr1 = xr0 + DD;
    ushort* xb0 = xb + (size_t)t0 * DD;
    ushort* xb1 = xb0 + DD;

#pragma unroll 4
    for (int s = 0; s < DD / 64; ++s) {
        const int d = s * 64 + lane;
        const float x0 = xr0[d];
        const float x1 = xr1[d];
        xb0[d] = f2bfu(x0);
        xb1[d] = f2bfu(x1);
        const float* row = &WT[d * 20];
        const float4 w0 = *(const float4*)(row + 0);    // Wr e0-3
        const float4 w1 = *(const float4*)(row + 4);    // Wr e4-7
        const float4 w2 = *(const float4*)(row + 8);    // Wn e0-3
        const float4 w3 = *(const float4*)(row + 12);   // Wn e4-7
        const float wr[8] = { w0.x, w0.y, w0.z, w0.w, w1.x, w1.y, w1.z, w1.w };
        const float wn[8] = { w2.x, w2.y, w2.z, w2.w, w3.x, w3.y, w3.z, w3.w };
#pragma unroll
        for (int e = 0; e < EE; ++e) {
            a0r[e] = fmaf(x0, wr[e], a0r[e]);
            a0n[e] = fmaf(x0, wn[e], a0n[e]);
            a1r[e] = fmaf(x1, wr[e], a1r[e]);
            a1n[e] = fmaf(x1, wn[e], a1n[e]);
        }
    }
#pragma unroll
    for (int off = 32; off > 0; off >>= 1) {
#pragma unroll
        for (int e = 0; e < EE; ++e) {
            a0r[e] += __shfl_xor(a0r[e], off);
            a0n[e] += __shfl_xor(a0n[e], off);
            a1r[e] += __shfl_xor(a1r[e], off);
            a1n[e] += __shfl_xor(a1n[e], off);
        }
    }
    if (lane == 0) {
        ROUTER_TAIL(a0r, a0n, t0);
        ROUTER_TAIL(a1r, a1n, t0 + 1);
    }
}

// ---------------------------------------------------------------------------
// Grouped GEMM v5: 128x128x64 tile, 4 waves (2x2), XOR-swizzled LDS,
// COUNTED-vmcnt double-buffer (T4):
//   per wave per K-tile: 8 global_load_lds. Loop: issue 8 loads for t+1 ->
//   s_waitcnt vmcnt(8)  (retires ONLY tile-t's loads, which had a full
//   iteration of MFMA to land) -> s_barrier -> compute t -> s_barrier.
//   Round-3's __syncthreads drained vmcnt(0) = the just-issued prefetch ->
//   zero overlap (the measured regression).
// T5: setprio(1) around the MFMA cluster (phase role-split now exists).
// Grid: bijective chunked XCD swizzle (m204): wid = (bx&7)*(NW/8) + bx>>3,
//   wid = tile*NSLICE + slice. With MAXMT=40, each XCD owns EXACTLY one
//   expert: its weight panels (~1 MB) stay L2-resident, A-sharing slices
//   are wid-adjacent.
// ---------------------------------------------------------------------------

// Kernel 4: down: hid[off+row][n] = gelu(x_gathered @ WdT^T + bd), 8 expert groups
__global__ __launch_bounds__(256) void down_k(
    const ushort* __restrict__ xb, const ushort* __restrict__ WdT, const float* __restrict__ bd,
    const int* __restrict__ cnt, const unsigned* __restrict__ entries, ushort* __restrict__ hid)
{
    const int bx = blockIdx.x;
    const int wid = (bx & 7) * (NWD >> 3) + (bx >> 3);
    const int n0 = (wid % NSL_D) * 128;
    const int tile = wid / NSL_D;
    const int tm = tile % MAXMT;
    const int g = tile / MAXMT, e = g;
    const int n_g = cnt[g * 16];
    if (tm * 128 >= n_g) return;

    int og = 0;
    for (int gg = 0; gg < g; ++gg) og += cnt[gg * 16];   // exclusive prefix

    __shared__ __align__(16) ushort As[2 * 128 * 64];
    __shared__ __align__(16) ushort Bs[2 * 128 * 64];
    __shared__ unsigned ecache[128];

    const int tid = threadIdx.x, lane = tid & 63, w = tid >> 6;
    const int wm = w >> 1, wn = w & 1;
    const int fr = lane & 15, fq = lane >> 4;

    if (tid < 128) {
        const int ridx = min(tm * 128 + tid, n_g - 1);
        ecache[tid] = entries[g * NTOK + ridx];
    }
    __syncthreads();

    const int lr = lane >> 3, seg = lane & 7;
    const int slog = seg ^ lr;                 // row&7 == lr for all j
    const ushort* gA[4]; const ushort* gB[4];
    int loff[4];
    const ushort* WTe = WdT + (size_t)e * HH * DD;
#pragma unroll
    for (int j = 0; j < 4; ++j) {
        const int row = w * 32 + j * 8 + lr;
        const int tok = (int)(ecache[row] & 0x3FFFu);
        gA[j] = xb + (size_t)tok * DD + slog * 8;
        gB[j] = WTe + (size_t)(n0 + row) * DD + slog * 8;
        loff[j] = (w * 256 + j * 64) * 16;     // byte offset within one buffer
    }

    floatx4 acc[4][4];
#pragma unroll
    for (int i = 0; i < 4; ++i)
#pragma unroll
        for (int j = 0; j < 4; ++j) acc[i][j] = (floatx4){0.f, 0.f, 0.f, 0.f};

    const int axr = wm * 64 + fr;
    const int bxr = wn * 64 + fr;

    // prologue: tile 0 -> buf 0 (8 glds per wave in flight)
#pragma unroll
    for (int j = 0; j < 4; ++j) {
        glds16(gA[j], (char*)As + loff[j]);
        glds16(gB[j], (char*)Bs + loff[j]);
    }

    int cur = 0;
    for (int k0 = 0; k0 < DD; k0 += 64) {
        if (k0 + 64 < DD) {
            const int nb = (cur ^ 1) * 16384;
#pragma unroll
            for (int j = 0; j < 4; ++j) {
                glds16(gA[j] + k0 + 64, (char*)As + nb + loff[j]);
                glds16(gB[j] + k0 + 64, (char*)Bs + nb + loff[j]);
            }
            asm volatile("s_waitcnt vmcnt(8)" ::: "memory");  // retire tile-t only
        } else {
            asm volatile("s_waitcnt vmcnt(0)" ::: "memory");  // last tile: drain
        }
        __builtin_amdgcn_sched_barrier(0);
        __builtin_amdgcn_s_barrier();          // all waves: tile-t fully in LDS
        asm volatile("" ::: "memory");
        const int cb = cur * 8192;
        __builtin_amdgcn_s_setprio(1);
#pragma unroll
        for (int kh = 0; kh < 2; ++kh) {
            short8 a[4], b[4];
#pragma unroll
            for (int mt = 0; mt < 4; ++mt) {
                const int r = axr + mt * 16;
                a[mt] = *(const short8*)&As[cb + r * 64 + ((kh * 4 + fq) ^ (r & 7)) * 8];
            }
#pragma unroll
            for (int nt = 0; nt < 4; ++nt) {
                const int r = bxr + nt * 16;
                b[nt] = *(const short8*)&Bs[cb + r * 64 + ((kh * 4 + fq) ^ (r & 7)) * 8];
            }
#pragma unroll
            for (int mt = 0; mt < 4; ++mt)
#pragma unroll
                for (int nt = 0; nt < 4; ++nt)
                    acc[mt][nt] = __builtin_amdgcn_mfma_f32_16x16x32_bf16(a[mt], b[nt], acc[mt][nt], 0, 0, 0);
        }
        __builtin_amdgcn_s_setprio(0);
        asm volatile("" ::: "memory");
        __builtin_amdgcn_s_barrier();          // reads of buf[cur] done before overwrite
        cur ^= 1;
    }

    const int hbase = og + tm * 128;
#pragma unroll
    for (int nt = 0; nt < 4; ++nt) {
        const int n = n0 + wn * 64 + nt * 16 + fr;
        const float bias = bd[e * HH + n];
#pragma unroll
        for (int mt = 0; mt < 4; ++mt)
#pragma unroll
            for (int i = 0; i < 4; ++i) {
                const int rl = wm * 64 + mt * 16 + fq * 4 + i;
                if (tm * 128 + rl < n_g) {
                    const float v = acc[mt][nt][i] + bias;
                    const float ge = 0.5f * v * (1.f + erff(v * 0.7071067811865475f));
                    hid[(size_t)(hbase + rl) * HH + n] = f2bfu(ge);
                }
            }
    }
}

// Kernel 5: up: slots[tok*2+slot][n] = (hid @ WuT^T + bu) * gate, 8 expert groups
__global__ __launch_bounds__(256) void up_k(
    const ushort* __restrict__ hid, const ushort* __restrict__ WuT, const float* __restrict__ bu,
    const int* __restrict__ cnt, const unsigned* __restrict__ entries, ushort* __restrict__ slots)
{
    const int bx = blockIdx.x;
    const int wid = (bx & 7) * (NWU >> 3) + (bx >> 3);
    const int n0 = (wid % NSL_U) * 128;
    const int tile = wid / NSL_U;
    const int tm = tile % MAXMT;
    const int g = tile / MAXMT, e = g;
    const int n_g = cnt[g * 16];
    if (tm * 128 >= n_g) return;

    int hbase = 0;
    for (int gg = 0; gg < g; ++gg) hbase += cnt[gg * 16];  // exclusive prefix

    __shared__ __align__(16) ushort As[2 * 128 * 64];
    __shared__ __align__(16) ushort Bs[2 * 128 * 64];
    __shared__ unsigned ecache[128];

    const int tid = threadIdx.x, lane = tid & 63, w = tid >> 6;
    const int wm = w >> 1, wn = w & 1;
    const int fr = lane & 15, fq = lane >> 4;

    if (tid < 128) {
        const int ridx = min(tm * 128 + tid, n_g - 1);
        ecache[tid] = entries[g * NTOK + ridx];
    }
    __syncthreads();

    const int lr = lane >> 3, seg = lane & 7;
    const int slog = seg ^ lr;
    const ushort* gA[4]; const ushort* gB[4];
    int loff[4];
    const ushort* WTe = WuT + (size_t)e * DD * HH;
#pragma unroll
    for (int j = 0; j < 4; ++j) {
        const int row = w * 32 + j * 8 + lr;
        const int ar = min(tm * 128 + row, n_g - 1);
        gA[j] = hid + (size_t)(hbase + ar) * HH + slog * 8;
        gB[j] = WTe + (size_t)(n0 + row) * HH + slog * 8;
        loff[j] = (w * 256 + j * 64) * 16;
    }

    floatx4 acc[4][4];
#pragma unroll
    for (int i = 0; i < 4; ++i)
#pragma unroll
        for (int j = 0; j < 4; ++j) acc[i][j] = (floatx4){0.f, 0.f, 0.f, 0.f};

    const int axr = wm * 64 + fr;
    const int bxr = wn * 64 + fr;

    // prologue: tile 0 -> buf 0
#pragma unroll
    for (int j = 0; j < 4; ++j) {
        glds16(gA[j], (char*)As + loff[j]);
        glds16(gB[j], (char*)Bs + loff[j]);
    }

    int cur = 0;
    for (int k0 = 0; k0 < HH; k0 += 64) {
        if (k0 + 64 < HH) {
            const int nb = (cur ^ 1) * 16384;
#pragma unroll
            for (int j = 0; j < 4; ++j) {
                glds16(gA[j] + k0 + 64, (char*)As + nb + loff[j]);
                glds16(gB[j] + k0 + 64, (char*)Bs + nb + loff[j]);
            }
            asm volatile("s_waitcnt vmcnt(8)" ::: "memory");
        } else {
            asm volatile("s_waitcnt vmcnt(0)" ::: "memory");
        }
        __builtin_amdgcn_sched_barrier(0);
        __builtin_amdgcn_s_barrier();
        asm volatile("" ::: "memory");
        const int cb = cur * 8192;
        __builtin_amdgcn_s_setprio(1);
#pragma unroll
        for (int kh = 0; kh < 2; ++kh) {
            short8 a[4], b[4];
#pragma unroll
            for (int mt = 0; mt < 4; ++mt) {
                const int r = axr + mt * 16;
                a[mt] = *(const short8*)&As[cb + r * 64 + ((kh * 4 + fq) ^ (r & 7)) * 8];
            }
#pragma unroll
            for (int nt = 0; nt < 4; ++nt) {
                const int r = bxr + nt * 16;
                b[nt] = *(const short8*)&Bs[cb + r * 64 + ((kh * 4 + fq) ^ (r & 7)) * 8];
            }
#pragma unroll
            for (int mt = 0; mt < 4; ++mt)
#pragma unroll
                for (int nt = 0; nt < 4; ++nt)
                    acc[mt][nt] = __builtin_amdgcn_mfma_f32_16x16x32_bf16(a[mt], b[nt], acc[mt][nt], 0, 0, 0);
        }
        __builtin_amdgcn_s_setprio(0);
        asm volatile("" ::: "memory");
        __builtin_amdgcn_s_barrier();
        cur ^= 1;
    }

#pragma unroll
    for (int nt = 0; nt < 4; ++nt) {
        const int n = n0 + wn * 64 + nt * 16 + fr;
        const float bias = bu[e * DD + n];
#pragma unroll
        for (int mt = 0; mt < 4; ++mt)
#pragma unroll
            for (int i = 0; i < 4; ++i) {
                const int rl = wm * 64 + mt * 16 + fq * 4 + i;
                if (tm * 128 + rl < n_g) {
                    const unsigned en = ecache[rl];
                    const int tok = (int)(en & 0x3FFFu);
                    const int slot = (int)((en >> 14) & 1u);
                    ushort hb = (ushort)(en >> 16);
                    const float gate = __half2float(*reinterpret_cast<__half*>(&hb));
                    const float v = (acc[mt][nt][i] + bias) * gate;
                    slots[((size_t)tok * 2 + slot) * DD + n] = f2bfu(v);
                }
            }
    }
}

// Kernel 6: out[t][d] = slots[2t][d] + slots[2t+1][d]  (fp32 out, 8 elems/thread)
__global__ __launch_bounds__(256) void combine_k(
    const ushort* __restrict__ slots, float* __restrict__ out)
{
    const size_t flat = ((size_t)blockIdx.x * 256 + threadIdx.x) * 8;
    const size_t t = flat >> 10;         // / DD
    const size_t d = flat & (DD - 1);
    union { uint4 v; ushort h[8]; } a, b;
    a.v = *(const uint4*)(slots + ((t * 2 + 0) << 10) + d);
    b.v = *(const uint4*)(slots + ((t * 2 + 1) << 10) + d);
    float o[8];
#pragma unroll
    for (int j = 0; j < 8; ++j) o[j] = bfu2f(a.h[j]) + bfu2f(b.h[j]);
    *(float4*)(out + flat) = *(const float4*)&o[0];
    *(float4*)(out + flat + 4) = *(const float4*)&o[4];
}

// ---------------------------------------------------------------------------
// Workspace layout (bytes), total ~145 MB:
//   0         cnt    : int[8] @ 64B stride (256-int region zeroed by trans_k)
//   2048      entries: u32[8][16384]             (0.5 MB)
//   1050624   xb     : bf16 [16384][1024]        (32 MB)
//   34605056  WdT    : bf16 [8][512 h][1024 d]   (8 MB)
//   42993664  WuT    : bf16 [8][1024 d][512 h]   (8 MB)
//   51382272  hid    : bf16 [32768][512]         (32 MB)
//   84936704  slots  : bf16 [32768][1024]        (64 MB)
// ---------------------------------------------------------------------------
extern "C" void kernel_launch(void* const* d_in, const int* in_sizes, int n_in,
                              void* d_out, int out_size, void* d_ws, size_t ws_size,
                              hipStream_t stream)
{
    const float* x     = (const float*)d_in[0];
    const float* Wr    = (const float*)d_in[1];
    const float* br    = (const float*)d_in[2];
    const float* Wn    = (const float*)d_in[3];
    const float* bn    = (const float*)d_in[4];
    const float* Wd    = (const float*)d_in[5];
    const float* bd    = (const float*)d_in[6];
    const float* Wu    = (const float*)d_in[7];
    const float* bu    = (const float*)d_in[8];
    const float* noise = (const float*)d_in[9];

    char* ws = (char*)d_ws;
    int*      cnt     = (int*)(ws + 0);
    unsigned* entries = (unsigned*)(ws + 2048);
    ushort*   xb      = (ushort*)(ws + 1050624);
    ushort*   WdT     = (ushort*)(ws + 34605056);
    ushort*   WuT     = (ushort*)(ws + 42993664);
    ushort*   hid     = (ushort*)(ws + 51382272);
    ushort*   slots   = (ushort*)(ws + 84936704);

    trans_k<<<dim3(HH / 64, DD / 64, EE), 256, 0, stream>>>(Wd, WdT, DD, HH, cnt);      // [d][h]->[h][d] + zero cnt
    trans_k<<<dim3(DD / 64, HH / 64, EE), 256, 0, stream>>>(Wu, WuT, HH, DD, nullptr);  // [h][d]->[d][h]
    router_k<<<NTOK / 16, 512, 0, stream>>>(x, Wr, br, Wn, bn, noise, cnt, entries, xb);
    down_k<<<NWD, 256, 0, stream>>>(xb, WdT, bd, cnt, entries, hid);
    up_k<<<NWU, 256, 0, stream>>>(hid, WuT, bu, cnt, entries, slots);
    combine_k<<<(NTOK * DD) / (256 * 8), 256, 0, stream>>>(slots, (float*)d_out);
}

// Round 7
// 431.801 us; speedup vs baseline: 1.0560x; 1.0361x over previous
//
#include <hip/hip_runtime.h>
#include <hip/hip_bf16.h>
#include <hip/hip_fp16.h>
#include <math.h>

// Problem constants
#define DD   1024
#define EE   8
#define HH   512
#define NTOK 16384        // B*T
#define MAXMT 40          // max 128-row tiles per expert (n_e ~ 4096, sigma ~60 -> 5120 is >>safe)
#define NSL_D 4           // down: N=512  -> 4 slices of 128
#define NSL_U 8           // up:   N=1024 -> 8 slices of 128
#define NWD  (EE * MAXMT * NSL_D)   // 1280 blocks, %8==0
#define NWU  (EE * MAXMT * NSL_U)   // 2560 blocks, %8==0

typedef __attribute__((ext_vector_type(8))) short short8;   // 8 bf16
typedef __attribute__((ext_vector_type(4))) float floatx4;  // MFMA C/D frag

__device__ __forceinline__ ushort f2bfu(float f) {
    __hip_bfloat16 h = __float2bfloat16(f);   // RNE
    return *reinterpret_cast<ushort*>(&h);
}
__device__ __forceinline__ float bfu2f(ushort u) {
    union { unsigned u; float f; } cv; cv.u = ((unsigned)u) << 16; return cv.f;
}

// async global->LDS, 16B per lane. LDS dest = wave-uniform base + lane*16.
__device__ __forceinline__ void glds16(const void* g, void* l) {
    __builtin_amdgcn_global_load_lds(
        (const __attribute__((address_space(1))) unsigned int*)g,
        (__attribute__((address_space(3))) unsigned int*)l, 16, 0, 0);
}

// ---------------------------------------------------------------------------
// Kernel 1: per-expert transpose + cvt: src [E][R][C] fp32 -> dst [E][C][R] bf16
// First launch also zeroes the 256-int counter region.
// ---------------------------------------------------------------------------
__global__ __launch_bounds__(256) void trans_k(const float* __restrict__ src, ushort* __restrict__ dst,
                                               const int R, const int C, int* __restrict__ cnt) {
    if (cnt && blockIdx.x == 0 && blockIdx.y == 0 && blockIdx.z == 0 && threadIdx.x < 256)
        cnt[threadIdx.x] = 0;
    const int e = blockIdx.z, r0 = blockIdx.y * 64, c0 = blockIdx.x * 64;
    __shared__ float t[64][65];
    const int tid = threadIdx.x;
    const int cseg = (tid & 15) * 4, rr = tid >> 4;
#pragma unroll
    for (int j = 0; j < 4; ++j) {
        const int r = rr + j * 16;
        const float4 v = *(const float4*)(src + ((size_t)e * R + r0 + r) * C + c0 + cseg);
        t[r][cseg] = v.x; t[r][cseg+1] = v.y; t[r][cseg+2] = v.z; t[r][cseg+3] = v.w;
    }
    __syncthreads();
    const int rseg = (tid & 15) * 4;
#pragma unroll
    for (int j = 0; j < 4; ++j) {
        const int crow = (tid >> 4) + j * 16;
        ushort o[4];
#pragma unroll
        for (int q = 0; q < 4; ++q) o[q] = f2bfu(t[rseg + q][crow]);
        *(uint2*)(dst + ((size_t)e * C + c0 + crow) * R + r0 + rseg) = *(uint2*)o;
    }
}

// ---------------------------------------------------------------------------
// Kernel 2: router + x->bf16 cvt. Weights staged in LDS (WT[d][20] fp32,
// exactly 80 KB -> 2 blocks/CU); 512 thr = 8 waves x 2 tokens.
// v5 (Guideline 12): entry publication via per-block LDS aggregation.
//   Old: 32768 BLOCKING atomicAdds (wave waits for returned offset) on 8
//   cachelines = 4096 serialized L2 RMWs/line ~ 50 us makespan (R6: router
//   117 us == R1's pre-LDS router; R2 with 16 lines was <107).
//   New: block collects its 32 (expert,payload) pairs in LDS (aliasing the
//   dead WT buffer - LDS stays 80 KB), then 8 threads do ONE atomicAdd per
//   expert per block (<=8192 total, 1024/line) and copy entries out.
// Group order within an expert is arbitrary -> GEMMs unaffected.
// entry payload = tok | slot<<14 | gate_f16<<16.
// ---------------------------------------------------------------------------
__device__ __forceinline__ void route_token(
    const float* ar, const float* an, int t,
    const float* __restrict__ br, const float* __restrict__ bn,
    const float* __restrict__ noise,
    unsigned& e0, unsigned& p0, unsigned& e1, unsigned& p1)
{
    float noisy[EE];
#pragma unroll
    for (int e = 0; e < EE; ++e) {
        const float lg = ar[e] + br[e];
        const float nl = an[e] + bn[e];
        const float sp = fmaxf(nl, 0.f) + log1pf(expf(-fabsf(nl)));
        noisy[e] = lg + noise[(size_t)t * EE + e] * sp;
    }
    int i0 = 0;
#pragma unroll
    for (int e = 1; e < EE; ++e) if (noisy[e] > noisy[i0]) i0 = e;
    int i1 = (i0 == 0) ? 1 : 0;
#pragma unroll
    for (int e = 0; e < EE; ++e) if (e != i0 && noisy[e] > noisy[i1]) i1 = e;
    const float ex = expf(noisy[i1] - noisy[i0]);
    const float g0 = 1.f / (1.f + ex);
    const float g1 = ex / (1.f + ex);
    __half h0 = __float2half_rn(g0), h1 = __float2half_rn(g1);
    e0 = (unsigned)i0;
    e1 = (unsigned)i1;
    p0 = (unsigned)t | ((unsigned)*reinterpret_cast<ushort*>(&h0) << 16);
    p1 = (unsigned)t | (1u << 14) | ((unsigned)*reinterpret_cast<ushort*>(&h1) << 16);
}

__global__ __launch_bounds__(512) void router_k(
    const float* __restrict__ x, const float* __restrict__ Wr, const float* __restrict__ br,
    const float* __restrict__ Wn, const float* __restrict__ bn, const float* __restrict__ noise,
    int* __restrict__ cnt, unsigned* __restrict__ entries, ushort* __restrict__ xb)
{
    __shared__ __align__(16) float WT[DD * 20];   // 80 KB; first 256B reused as agg buffer at the tail

    const int tid = threadIdx.x;
    // ---- stage Wr/Wn -> WT[d][20] (coalesced global float4 reads) ----
    {
        const int d0 = tid * 2;
#pragma unroll
        for (int r = 0; r < 2; ++r) {
            const int d = d0 + r;
            float4 a = *(const float4*)(Wr + (size_t)d * EE);
            float4 b = *(const float4*)(Wr + (size_t)d * EE + 4);
            float4 c = *(const float4*)(Wn + (size_t)d * EE);
            float4 e4 = *(const float4*)(Wn + (size_t)d * EE + 4);
            float* row = &WT[d * 20];
            *(float4*)(row + 0)  = a;
            *(float4*)(row + 4)  = b;
            *(float4*)(row + 8)  = c;
            *(float4*)(row + 12) = e4;
        }
    }
    __syncthreads();

    const int wave = tid >> 6;
    const int lane = tid & 63;
    const int t0 = blockIdx.x * 16 + wave * 2;

    float a0r[EE], a0n[EE], a1r[EE], a1n[EE];
#pragma unroll
    for (int e = 0; e < EE; ++e) { a0r[e] = 0.f; a0n[e] = 0.f; a1r[e] = 0.f; a1n[e] = 0.f; }

    const float* xr0 = x + (size_t)t0 * DD;
    const float* xr1 = xr0 + DD;
    ushort* xb0 = xb + (size_t)t0 * DD;
    ushort* xb1 = xb0 + DD;

#pragma unroll 4
    for (int s = 0; s < DD / 64; ++s) {
        const int d = s * 64 + lane;
        const float x0 = xr0[d];
        const float x1 = xr1[d];
        xb0[d] = f2bfu(x0);
        xb1[d] = f2bfu(x1);
        const float* row = &WT[d * 20];
        const float4 w0 = *(const float4*)(row + 0);    // Wr e0-3
        const float4 w1 = *(const float4*)(row + 4);    // Wr e4-7
        const float4 w2 = *(const float4*)(row + 8);    // Wn e0-3
        const float4 w3 = *(const float4*)(row + 12);   // Wn e4-7
        const float wr[8] = { w0.x, w0.y, w0.z, w0.w, w1.x, w1.y, w1.z, w1.w };
        const float wn[8] = { w2.x, w2.y, w2.z, w2.w, w3.x, w3.y, w3.z, w3.w };
#pragma unroll
        for (int e = 0; e < EE; ++e) {
            a0r[e] = fmaf(x0, wr[e], a0r[e]);
            a0n[e] = fmaf(x0, wn[e], a0n[e]);
            a1r[e] = fmaf(x1, wr[e], a1r[e]);
            a1n[e] = fmaf(x1, wn[e], a1n[e]);
        }
    }
#pragma unroll
    for (int off = 32; off > 0; off >>= 1) {
#pragma unroll
        for (int e = 0; e < EE; ++e) {
            a0r[e] += __shfl_xor(a0r[e], off);
            a0n[e] += __shfl_xor(a0n[e], off);
            a1r[e] += __shfl_xor(a1r[e], off);
            a1n[e] += __shfl_xor(a1n[e], off);
        }
    }

    unsigned e0a, p0a, e1a, p1a, e0b, p0b, e1b, p1b;
    if (lane == 0) {
        route_token(a0r, a0n, t0,     br, bn, noise, e0a, p0a, e1a, p1a);
        route_token(a1r, a1n, t0 + 1, br, bn, noise, e0b, p0b, e1b, p1b);
    }

    __syncthreads();    // all waves done reading WT -> safe to alias
    unsigned* aggp = (unsigned*)WT;        // [32] payloads
    unsigned* agge = aggp + 32;            // [32] expert ids
    if (lane == 0) {
        const int b = wave * 4;
        aggp[b + 0] = p0a; agge[b + 0] = e0a;
        aggp[b + 1] = p1a; agge[b + 1] = e1a;
        aggp[b + 2] = p0b; agge[b + 2] = e0b;
        aggp[b + 3] = p1b; agge[b + 3] = e1b;
    }
    __syncthreads();
    if (tid < EE) {
        int c = 0;
#pragma unroll
        for (int j = 0; j < 32; ++j) c += (agge[j] == (unsigned)tid);
        if (c) {
            int base = atomicAdd(&cnt[tid * 16], c);
            for (int j = 0; j < 32; ++j)
                if (agge[j] == (unsigned)tid) entries[tid * NTOK + (base++)] = aggp[j];
        }
    }
}

// ---------------------------------------------------------------------------
// Grouped GEMM v5 (unchanged from round 6 for attribution): 128x128x64 tile,
// 4 waves (2x2), XOR-swizzled LDS, COUNTED-vmcnt double-buffer (T4),
// T5 setprio around MFMA, bijective chunked XCD swizzle (expert-per-XCD).
// ---------------------------------------------------------------------------

// Kernel 4: down: hid[off+row][n] = gelu(x_gathered @ WdT^T + bd), 8 expert groups
__global__ __launch_bounds__(256) void down_k(
    const ushort* __restrict__ xb, const ushort* __restrict__ WdT, const float* __restrict__ bd,
    const int* __restrict__ cnt, const unsigned* __restrict__ entries, ushort* __restrict__ hid)
{
    const int bx = blockIdx.x;
    const int wid = (bx & 7) * (NWD >> 3) + (bx >> 3);
    const int n0 = (wid % NSL_D) * 128;
    const int tile = wid / NSL_D;
    const int tm = tile % MAXMT;
    const int g = tile / MAXMT, e = g;
    const int n_g = cnt[g * 16];
    if (tm * 128 >= n_g) return;

    int og = 0;
    for (int gg = 0; gg < g; ++gg) og += cnt[gg * 16];   // exclusive prefix

    __shared__ __align__(16) ushort As[2 * 128 * 64];
    __shared__ __align__(16) ushort Bs[2 * 128 * 64];
    __shared__ unsigned ecache[128];

    const int tid = threadIdx.x, lane = tid & 63, w = tid >> 6;
    const int wm = w >> 1, wn = w & 1;
    const int fr = lane & 15, fq = lane >> 4;

    if (tid < 128) {
        const int ridx = min(tm * 128 + tid, n_g - 1);
        ecache[tid] = entries[g * NTOK + ridx];
    }
    __syncthreads();

    const int lr = lane >> 3, seg = lane & 7;
    const int slog = seg ^ lr;                 // row&7 == lr for all j
    const ushort* gA[4]; const ushort* gB[4];
    int loff[4];
    const ushort* WTe = WdT + (size_t)e * HH * DD;
#pragma unroll
    for (int j = 0; j < 4; ++j) {
        const int row = w * 32 + j * 8 + lr;
        const int tok = (int)(ecache[row] & 0x3FFFu);
        gA[j] = xb + (size_t)tok * DD + slog * 8;
        gB[j] = WTe + (size_t)(n0 + row) * DD + slog * 8;
        loff[j] = (w * 256 + j * 64) * 16;     // byte offset within one buffer
    }

    floatx4 acc[4][4];
#pragma unroll
    for (int i = 0; i < 4; ++i)
#pragma unroll
        for (int j = 0; j < 4; ++j) acc[i][j] = (floatx4){0.f, 0.f, 0.f, 0.f};

    const int axr = wm * 64 + fr;
    const int bxr = wn * 64 + fr;

    // prologue: tile 0 -> buf 0 (8 glds per wave in flight)
#pragma unroll
    for (int j = 0; j < 4; ++j) {
        glds16(gA[j], (char*)As + loff[j]);
        glds16(gB[j], (char*)Bs + loff[j]);
    }

    int cur = 0;
    for (int k0 = 0; k0 < DD; k0 += 64) {
        if (k0 + 64 < DD) {
            const int nb = (cur ^ 1) * 16384;
#pragma unroll
            for (int j = 0; j < 4; ++j) {
                glds16(gA[j] + k0 + 64, (char*)As + nb + loff[j]);
                glds16(gB[j] + k0 + 64, (char*)Bs + nb + loff[j]);
            }
            asm volatile("s_waitcnt vmcnt(8)" ::: "memory");  // retire tile-t only
        } else {
            asm volatile("s_waitcnt vmcnt(0)" ::: "memory");  // last tile: drain
        }
        __builtin_amdgcn_sched_barrier(0);
        __builtin_amdgcn_s_barrier();          // all waves: tile-t fully in LDS
        asm volatile("" ::: "memory");
        const int cb = cur * 8192;
        __builtin_amdgcn_s_setprio(1);
#pragma unroll
        for (int kh = 0; kh < 2; ++kh) {
            short8 a[4], b[4];
#pragma unroll
            for (int mt = 0; mt < 4; ++mt) {
                const int r = axr + mt * 16;
                a[mt] = *(const short8*)&As[cb + r * 64 + ((kh * 4 + fq) ^ (r & 7)) * 8];
            }
#pragma unroll
            for (int nt = 0; nt < 4; ++nt) {
                const int r = bxr + nt * 16;
                b[nt] = *(const short8*)&Bs[cb + r * 64 + ((kh * 4 + fq) ^ (r & 7)) * 8];
            }
#pragma unroll
            for (int mt = 0; mt < 4; ++mt)
#pragma unroll
                for (int nt = 0; nt < 4; ++nt)
                    acc[mt][nt] = __builtin_amdgcn_mfma_f32_16x16x32_bf16(a[mt], b[nt], acc[mt][nt], 0, 0, 0);
        }
        __builtin_amdgcn_s_setprio(0);
        asm volatile("" ::: "memory");
        __builtin_amdgcn_s_barrier();          // reads of buf[cur] done before overwrite
        cur ^= 1;
    }

    const int hbase = og + tm * 128;
#pragma unroll
    for (int nt = 0; nt < 4; ++nt) {
        const int n = n0 + wn * 64 + nt * 16 + fr;
        const float bias = bd[e * HH + n];
#pragma unroll
        for (int mt = 0; mt < 4; ++mt)
#pragma unroll
            for (int i = 0; i < 4; ++i) {
                const int rl = wm * 64 + mt * 16 + fq * 4 + i;
                if (tm * 128 + rl < n_g) {
                    const float v = acc[mt][nt][i] + bias;
                    const float ge = 0.5f * v * (1.f + erff(v * 0.7071067811865475f));
                    hid[(size_t)(hbase + rl) * HH + n] = f2bfu(ge);
                }
            }
    }
}

// Kernel 5: up: slots[tok*2+slot][n] = (hid @ WuT^T + bu) * gate, 8 expert groups
__global__ __launch_bounds__(256) void up_k(
    const ushort* __restrict__ hid, const ushort* __restrict__ WuT, const float* __restrict__ bu,
    const int* __restrict__ cnt, const unsigned* __restrict__ entries, ushort* __restrict__ slots)
{
    const int bx = blockIdx.x;
    const int wid = (bx & 7) * (NWU >> 3) + (bx >> 3);
    const int n0 = (wid % NSL_U) * 128;
    const int tile = wid / NSL_U;
    const int tm = tile % MAXMT;
    const int g = tile / MAXMT, e = g;
    const int n_g = cnt[g * 16];
    if (tm * 128 >= n_g) return;

    int hbase = 0;
    for (int gg = 0; gg < g; ++gg) hbase += cnt[gg * 16];  // exclusive prefix

    __shared__ __align__(16) ushort As[2 * 128 * 64];
    __shared__ __align__(16) ushort Bs[2 * 128 * 64];
    __shared__ unsigned ecache[128];

    const int tid = threadIdx.x, lane = tid & 63, w = tid >> 6;
    const int wm = w >> 1, wn = w & 1;
    const int fr = lane & 15, fq = lane >> 4;

    if (tid < 128) {
        const int ridx = min(tm * 128 + tid, n_g - 1);
        ecache[tid] = entries[g * NTOK + ridx];
    }
    __syncthreads();

    const int lr = lane >> 3, seg = lane & 7;
    const int slog = seg ^ lr;
    const ushort* gA[4]; const ushort* gB[4];
    int loff[4];
    const ushort* WTe = WuT + (size_t)e * DD * HH;
#pragma unroll
    for (int j = 0; j < 4; ++j) {
        const int row = w * 32 + j * 8 + lr;
        const int ar = min(tm * 128 + row, n_g - 1);
        gA[j] = hid + (size_t)(hbase + ar) * HH + slog * 8;
        gB[j] = WTe + (size_t)(n0 + row) * HH + slog * 8;
        loff[j] = (w * 256 + j * 64) * 16;
    }

    floatx4 acc[4][4];
#pragma unroll
    for (int i = 0; i < 4; ++i)
#pragma unroll
        for (int j = 0; j < 4; ++j) acc[i][j] = (floatx4){0.f, 0.f, 0.f, 0.f};

    const int axr = wm * 64 + fr;
    const int bxr = wn * 64 + fr;

    // prologue: tile 0 -> buf 0
#pragma unroll
    for (int j = 0; j < 4; ++j) {
        glds16(gA[j], (char*)As + loff[j]);
        glds16(gB[j], (char*)Bs + loff[j]);
    }

    int cur = 0;
    for (int k0 = 0; k0 < HH; k0 += 64) {
        if (k0 + 64 < HH) {
            const int nb = (cur ^ 1) * 16384;
#pragma unroll
            for (int j = 0; j < 4; ++j) {
                glds16(gA[j] + k0 + 64, (char*)As + nb + loff[j]);
                glds16(gB[j] + k0 + 64, (char*)Bs + nb + loff[j]);
            }
            asm volatile("s_waitcnt vmcnt(8)" ::: "memory");
        } else {
            asm volatile("s_waitcnt vmcnt(0)" ::: "memory");
        }
        __builtin_amdgcn_sched_barrier(0);
        __builtin_amdgcn_s_barrier();
        asm volatile("" ::: "memory");
        const int cb = cur * 8192;
        __builtin_amdgcn_s_setprio(1);
#pragma unroll
        for (int kh = 0; kh < 2; ++kh) {
            short8 a[4], b[4];
#pragma unroll
            for (int mt = 0; mt < 4; ++mt) {
                const int r = axr + mt * 16;
                a[mt] = *(const short8*)&As[cb + r * 64 + ((kh * 4 + fq) ^ (r & 7)) * 8];
            }
#pragma unroll
            for (int nt = 0; nt < 4; ++nt) {
                const int r = bxr + nt * 16;
                b[nt] = *(const short8*)&Bs[cb + r * 64 + ((kh * 4 + fq) ^ (r & 7)) * 8];
            }
#pragma unroll
            for (int mt = 0; mt < 4; ++mt)
#pragma unroll
                for (int nt = 0; nt < 4; ++nt)
                    acc[mt][nt] = __builtin_amdgcn_mfma_f32_16x16x32_bf16(a[mt], b[nt], acc[mt][nt], 0, 0, 0);
        }
        __builtin_amdgcn_s_setprio(0);
        asm volatile("" ::: "memory");
        __builtin_amdgcn_s_barrier();
        cur ^= 1;
    }

#pragma unroll
    for (int nt = 0; nt < 4; ++nt) {
        const int n = n0 + wn * 64 + nt * 16 + fr;
        const float bias = bu[e * DD + n];
#pragma unroll
        for (int mt = 0; mt < 4; ++mt)
#pragma unroll
            for (int i = 0; i < 4; ++i) {
                const int rl = wm * 64 + mt * 16 + fq * 4 + i;
                if (tm * 128 + rl < n_g) {
                    const unsigned en = ecache[rl];
                    const int tok = (int)(en & 0x3FFFu);
                    const int slot = (int)((en >> 14) & 1u);
                    ushort hb = (ushort)(en >> 16);
                    const float gate = __half2float(*reinterpret_cast<__half*>(&hb));
                    const float v = (acc[mt][nt][i] + bias) * gate;
                    slots[((size_t)tok * 2 + slot) * DD + n] = f2bfu(v);
                }
            }
    }
}

// Kernel 6: out[t][d] = slots[2t][d] + slots[2t+1][d]  (fp32 out, 8 elems/thread)
__global__ __launch_bounds__(256) void combine_k(
    const ushort* __restrict__ slots, float* __restrict__ out)
{
    const size_t flat = ((size_t)blockIdx.x * 256 + threadIdx.x) * 8;
    const size_t t = flat >> 10;         // / DD
    const size_t d = flat & (DD - 1);
    union { uint4 v; ushort h[8]; } a, b;
    a.v = *(const uint4*)(slots + ((t * 2 + 0) << 10) + d);
    b.v = *(const uint4*)(slots + ((t * 2 + 1) << 10) + d);
    float o[8];
#pragma unroll
    for (int j = 0; j < 8; ++j) o[j] = bfu2f(a.h[j]) + bfu2f(b.h[j]);
    *(float4*)(out + flat) = *(const float4*)&o[0];
    *(float4*)(out + flat + 4) = *(const float4*)&o[4];
}

// ---------------------------------------------------------------------------
// Workspace layout (bytes), total ~145 MB:
//   0         cnt    : int[8] @ 64B stride (256-int region zeroed by trans_k)
//   2048      entries: u32[8][16384]             (0.5 MB)
//   1050624   xb     : bf16 [16384][1024]        (32 MB)
//   34605056  WdT    : bf16 [8][512 h][1024 d]   (8 MB)
//   42993664  WuT    : bf16 [8][1024 d][512 h]   (8 MB)
//   51382272  hid    : bf16 [32768][512]         (32 MB)
//   84936704  slots  : bf16 [32768][1024]        (64 MB)
// ---------------------------------------------------------------------------
extern "C" void kernel_launch(void* const* d_in, const int* in_sizes, int n_in,
                              void* d_out, int out_size, void* d_ws, size_t ws_size,
                              hipStream_t stream)
{
    const float* x     = (const float*)d_in[0];
    const float* Wr    = (const float*)d_in[1];
    const float* br    = (const float*)d_in[2];
    const float* Wn    = (const float*)d_in[3];
    const float* bn    = (const float*)d_in[4];
    const float* Wd    = (const float*)d_in[5];
    const float* bd    = (const float*)d_in[6];
    const float* Wu    = (const float*)d_in[7];
    const float* bu    = (const float*)d_in[8];
    const float* noise = (const float*)d_in[9];

    char* ws = (char*)d_ws;
    int*      cnt     = (int*)(ws + 0);
    unsigned* entries = (unsigned*)(ws + 2048);
    ushort*   xb      = (ushort*)(ws + 1050624);
    ushort*   WdT     = (ushort*)(ws + 34605056);
    ushort*   WuT     = (ushort*)(ws + 42993664);
    ushort*   hid     = (ushort*)(ws + 51382272);
    ushort*   slots   = (ushort*)(ws + 84936704);

    trans_k<<<dim3(HH / 64, DD / 64, EE), 256, 0, stream>>>(Wd, WdT, DD, HH, cnt);      // [d][h]->[h][d] + zero cnt
    trans_k<<<dim3(DD / 64, HH / 64, EE), 256, 0, stream>>>(Wu, WuT, HH, DD, nullptr);  // [h][d]->[d][h]
    router_k<<<NTOK / 16, 512, 0, stream>>>(x, Wr, br, Wn, bn, noise, cnt, entries, xb);
    down_k<<<NWD, 256, 0, stream>>>(xb, WdT, bd, cnt, entries, hid);
    up_k<<<NWU, 256, 0, stream>>>(hid, WuT, bu, cnt, entries, slots);
    combine_k<<<(NTOK * DD) / (256 * 8), 256, 0, stream>>>(slots, (float*)d_out);
}